// Round 1
// 592.897 us; speedup vs baseline: 1.1891x; 1.1891x over previous
//
#include <hip/hip_runtime.h>
#include <hip/hip_bf16.h>

typedef __hip_bfloat16 bf16;
typedef __attribute__((ext_vector_type(8))) short bf16x8;
typedef __attribute__((ext_vector_type(4))) float f32x4;

#define NSTEP 6

static __device__ __forceinline__ float b2f(bf16 v) { return __bfloat162float(v); }

// dtype-dispatched param load: md==0 -> bf16, md==1 -> float32
static __device__ __forceinline__ float ldp(const void* p, int i, int md) {
    return md ? ((const float*)p)[i] : b2f(((const bf16*)p)[i]);
}
static __device__ __forceinline__ float finz(float v) {
    return (v == v && v * 0.0f == 0.0f) ? v : 0.0f;  // non-finite -> 0
}
static __device__ __forceinline__ unsigned short f2bfu(float v) {
    bf16 h = __float2bfloat16(v);
    return *(unsigned short*)&h;
}

// 8 consecutive bf16 -> 8 floats (one 16B load; works for global and LDS)
static __device__ __forceinline__ void ld_bf8(const bf16* p, float* f) {
    union { uint4 u; unsigned short s[8]; } r;
    r.u = *(const uint4*)p;
#pragma unroll
    for (int j = 0; j < 8; ++j) f[j] = __uint_as_float(((unsigned)r.s[j]) << 16);
}
// dtype-dispatched 8-wide param load (i multiple of 8)
static __device__ __forceinline__ void ldp8(const void* p, int i, int md, float* f) {
    if (md) {
        const float* fp = (const float*)p + i;
        float4 a = *(const float4*)fp, b = *(const float4*)(fp + 4);
        f[0]=a.x; f[1]=a.y; f[2]=a.z; f[3]=a.w; f[4]=b.x; f[5]=b.y; f[6]=b.z; f[7]=b.w;
    } else {
        ld_bf8((const bf16*)p + i, f);
    }
}
// pack 8 floats -> uint4 of bf16 (RNE)
static __device__ __forceinline__ uint4 pk_bf8(const float* f) {
    union { uint4 u; unsigned short s[8]; } r;
#pragma unroll
    for (int j = 0; j < 8; ++j) r.s[j] = f2bfu(f[j]);
    return r.u;
}

// ---------------- detect / pack / cast kernels ----------------

// flags[0]: masks dtype mode (0 int32, 1 u8, 2 16-bit, 3 f32)
// flags[1]: float-array dtype (0 bf16, 1 f32); also zeroes accv (96 floats)
__global__ void k_detect(const uint4* __restrict__ m4,
                         const uint4* __restrict__ x4,
                         int* __restrict__ flags, float* __restrict__ accv) {
    __shared__ int s3f, sup, slo, sf32;
    int t = threadIdx.x;
    if (t == 0) { s3f = 0; sup = 0; slo = 0; sf32 = 0; }
    if (t < 96) accv[t] = 0.f;
    __syncthreads();
    int l3f = 0, lup = 0, llo = 0, lf = 0;
    for (int i = t; i < 3072; i += 256) {
        uint4 v = m4[i];
        const unsigned* d = (const unsigned*)&v;
#pragma unroll
        for (int j = 0; j < 4; ++j) {
            unsigned w = d[j];
            unsigned x3f = w ^ 0x3F3F3F3Fu;
            if ((x3f - 0x01010101u) & ~x3f & 0x80808080u) l3f = 1;
            if (w & 0xFFFFFF00u) lup = 1;
            if (w & 0x0000FFFFu) llo = 1;
        }
    }
    for (int i = t; i < 4096; i += 256) {
        uint4 v = x4[i];
        const unsigned* d = (const unsigned*)&v;
#pragma unroll
        for (int j = 0; j < 4; ++j) {
            unsigned bb = (d[j] >> 8) & 0x7Fu;
            if (bb > 0x48u) lf = 1;
        }
    }
    if (l3f) atomicOr(&s3f, 1);
    if (lup) atomicOr(&sup, 1);
    if (llo) atomicOr(&slo, 1);
    if (lf)  atomicOr(&sf32, 1);
    __syncthreads();
    if (t == 0) {
        int mode;
        if (!s3f && !sup) mode = 0;
        else if (!s3f)    mode = 1;
        else if (slo)     mode = 2;
        else              mode = 3;
        flags[0] = mode;
        flags[1] = sf32;
    }
}

__global__ void k_cast(const void* __restrict__ in, float* __restrict__ out,
                       const int* __restrict__ mflags, int n8) {
    int md = mflags[1];
    int i = blockIdx.x * 256 + threadIdx.x;
    if (i < n8) {
        float f[8];
        ldp8(in, i * 8, md, f);
#pragma unroll
        for (int j = 0; j < 8; ++j) f[j] = finz(f[j]);
        *(float4*)&out[i * 8]     = make_float4(f[0], f[1], f[2], f[3]);
        *(float4*)&out[i * 8 + 4] = make_float4(f[4], f[5], f[6], f[7]);
    }
}

// fused straight bf16 packs (row-major [o][k] weights for the MFMA kernels):
// [0,24576) fc0w | [24576,32768) fc1w | [32768,45056) qkvw
// [45056,49152) outw | [49152,53248) ff1w | [53248,57344) ff2w
__global__ void k_pack_multi(const void* __restrict__ pa, const void* __restrict__ pb,
                             const void* __restrict__ pc, const void* __restrict__ pd,
                             const void* __restrict__ pe, const void* __restrict__ pf,
                             short* __restrict__ out, const int* __restrict__ mflags) {
    int md = mflags[1];
    int i = blockIdx.x * 256 + threadIdx.x;
    if (i >= 57344) return;
    float v;
    if      (i < 24576) v = ldp(pa, i, md);
    else if (i < 32768) v = ldp(pb, i - 24576, md);
    else if (i < 45056) v = ldp(pc, i - 32768, md);
    else if (i < 49152) v = ldp(pd, i - 45056, md);
    else if (i < 53248) v = ldp(pe, i - 49152, md);
    else                v = ldp(pf, i - 53248, md);
    out[i] = (short)f2bfu(v);
}

// bt1[o][k] bf16, k = (ky*3+kx)*64 + i ; o<64 -> p0_w, else p1_w ([O][I][3][3])
__global__ void k_pack_bt1(const void* __restrict__ p0, const void* __restrict__ p1,
                           short* __restrict__ out, const int* __restrict__ mflags) {
    int md = mflags[1];
    int i = blockIdx.x * 256 + threadIdx.x;
    if (i < 128 * 576) {
        int o = i / 576, k = i % 576;
        int kk = k >> 6, ii = k & 63;
        float v = (o < 64) ? ldp(p0, o * 576 + ii * 9 + kk, md)
                           : ldp(p1, (o - 64) * 576 + ii * 9 + kk, md);
        out[i] = (short)f2bfu(v);
    }
}

// ---------------- step kernels ----------------
// grid 512 = B*H rows, 512 threads (8 waves) per block.

// A (MFMA): conv-as-implicit-GEMM [64x128x576] + fc0 GEMM [64x128x192]
__global__ __launch_bounds__(512) void k_perceive(
    const float* __restrict__ xin, const short* __restrict__ bt1,
    const short* __restrict__ fc0s, const void* __restrict__ p0b,
    const void* __restrict__ p1b, const void* __restrict__ fc0b,
    const int* __restrict__ mflags, bf16* __restrict__ hd,
    float* __restrict__ accv, int step)
{
    __shared__ __align__(16) short xpad_s[3 * 66 * 72];
    __shared__ __align__(16) short P_s[64 * 200];
    __shared__ float red[32];
    int md = mflags[1];
    int bh = blockIdx.x;
    int b = bh >> 6, h = bh & 63;
    int t = threadIdx.x;

    for (int e = t; e < 1536; e += 512) {
        int c8 = e & 7, w = (e >> 3) & 63, r = e >> 9;
        int hr = h - 1 + r; hr = hr < 0 ? -hr : (hr > 63 ? 126 - hr : hr);
        const float* src = xin + ((((b << 6) + hr) << 6) | w) * 64 + c8 * 8;
        float f[8];
        float4 v0 = *(const float4*)src, v1 = *(const float4*)(src + 4);
        f[0]=v0.x; f[1]=v0.y; f[2]=v0.z; f[3]=v0.w; f[4]=v1.x; f[5]=v1.y; f[6]=v1.z; f[7]=v1.w;
        uint4 pv = pk_bf8(f);
        *(uint4*)&xpad_s[((r * 66) + w + 1) * 72 + c8 * 8] = pv;
        if (r == 1) *(uint4*)&P_s[w * 200 + c8 * 8] = pv;
    }
    if (t < 48) {
        int c8 = t & 7, side = (t >> 3) & 1, r = t >> 4;
        int hr = h - 1 + r; hr = hr < 0 ? -hr : (hr > 63 ? 126 - hr : hr);
        int wsrc = side ? 62 : 1, wp = side ? 65 : 0;
        const float* src = xin + ((((b << 6) + hr) << 6) | wsrc) * 64 + c8 * 8;
        float f[8];
        float4 v0 = *(const float4*)src, v1 = *(const float4*)(src + 4);
        f[0]=v0.x; f[1]=v0.y; f[2]=v0.z; f[3]=v0.w; f[4]=v1.x; f[5]=v1.y; f[6]=v1.z; f[7]=v1.w;
        *(uint4*)&xpad_s[((r * 66) + wp) * 72 + c8 * 8] = pk_bf8(f);
    }
    __syncthreads();

    int og  = __builtin_amdgcn_readfirstlane(t >> 6);
    int l   = t & 63, nl = l & 15, q = l >> 4;
    int mt0 = (og & 1) * 2;
    int nt0 = (og >> 1) * 2;
    int o0  = nt0 * 16 + nl, o1 = o0 + 16;

    f32x4 acc[2][2];
#pragma unroll
    for (int i = 0; i < 2; ++i)
#pragma unroll
        for (int j = 0; j < 2; ++j) acc[i][j] = (f32x4){0.f, 0.f, 0.f, 0.f};

    for (int kt = 0; kt < 18; ++kt) {
        int kk = kt >> 1, c0 = (kt & 1) << 5;
        int r = kk / 3, cxi = kk - r * 3;
        bf16x8 b0 = *(const bf16x8*)(bt1 + o0 * 576 + kt * 32 + q * 8);
        bf16x8 b1 = *(const bf16x8*)(bt1 + o1 * 576 + kt * 32 + q * 8);
        bf16x8 a0 = *(const bf16x8*)&xpad_s[((r * 66) + mt0 * 16 + nl + cxi) * 72 + c0 + q * 8];
        bf16x8 a1 = *(const bf16x8*)&xpad_s[((r * 66) + mt0 * 16 + 16 + nl + cxi) * 72 + c0 + q * 8];
        acc[0][0] = __builtin_amdgcn_mfma_f32_16x16x32_bf16(a0, b0, acc[0][0], 0, 0, 0);
        acc[0][1] = __builtin_amdgcn_mfma_f32_16x16x32_bf16(a0, b1, acc[0][1], 0, 0, 0);
        acc[1][0] = __builtin_amdgcn_mfma_f32_16x16x32_bf16(a1, b0, acc[1][0], 0, 0, 0);
        acc[1][1] = __builtin_amdgcn_mfma_f32_16x16x32_bf16(a1, b1, acc[1][1], 0, 0, 0);
    }
    {
        float bias0 = (o0 < 64) ? ldp(p0b, o0, md) : ldp(p1b, o0 - 64, md);
        float bias1 = (o1 < 64) ? ldp(p0b, o1, md) : ldp(p1b, o1 - 64, md);
#pragma unroll
        for (int i = 0; i < 2; ++i)
#pragma unroll
            for (int j = 0; j < 2; ++j) {
                int oo = j ? o1 : o0;
                float bb = j ? bias1 : bias0;
#pragma unroll
                for (int r2 = 0; r2 < 4; ++r2) {
                    int m = (mt0 + i) * 16 + q * 4 + r2;
                    P_s[m * 200 + 64 + oo] = (short)f2bfu(acc[i][j][r2] + bb);
                }
            }
    }
    __syncthreads();

#pragma unroll
    for (int i = 0; i < 2; ++i)
#pragma unroll
        for (int j = 0; j < 2; ++j) acc[i][j] = (f32x4){0.f, 0.f, 0.f, 0.f};
    for (int kt = 0; kt < 6; ++kt) {
        bf16x8 b0 = *(const bf16x8*)(fc0s + o0 * 192 + kt * 32 + q * 8);
        bf16x8 b1 = *(const bf16x8*)(fc0s + o1 * 192 + kt * 32 + q * 8);
        bf16x8 a0 = *(const bf16x8*)&P_s[(mt0 * 16 + nl) * 200 + kt * 32 + q * 8];
        bf16x8 a1 = *(const bf16x8*)&P_s[(mt0 * 16 + 16 + nl) * 200 + kt * 32 + q * 8];
        acc[0][0] = __builtin_amdgcn_mfma_f32_16x16x32_bf16(a0, b0, acc[0][0], 0, 0, 0);
        acc[0][1] = __builtin_amdgcn_mfma_f32_16x16x32_bf16(a0, b1, acc[0][1], 0, 0, 0);
        acc[1][0] = __builtin_amdgcn_mfma_f32_16x16x32_bf16(a1, b0, acc[1][0], 0, 0, 0);
        acc[1][1] = __builtin_amdgcn_mfma_f32_16x16x32_bf16(a1, b1, acc[1][1], 0, 0, 0);
    }
    float lsum = 0.f, lsq = 0.f;
    {
        float fb0 = ldp(fc0b, o0, md), fb1 = ldp(fc0b, o1, md);
#pragma unroll
        for (int i = 0; i < 2; ++i)
#pragma unroll
            for (int j = 0; j < 2; ++j) {
                int oo = j ? o1 : o0;
                float bb = j ? fb1 : fb0;
#pragma unroll
                for (int r2 = 0; r2 < 4; ++r2) {
                    int m = (mt0 + i) * 16 + q * 4 + r2;
                    float v = fmaxf(acc[i][j][r2] + bb, 0.f);
                    unsigned short hu = f2bfu(v);
                    hd[((bh << 6) + m) * 128 + oo] = *(bf16*)&hu;
                    float vr = __uint_as_float(((unsigned)hu) << 16);
                    lsum += vr; lsq += vr * vr;
                }
            }
    }
#pragma unroll
    for (int off = 32; off > 0; off >>= 1) {
        lsum += __shfl_down(lsum, off, 64);
        lsq  += __shfl_down(lsq,  off, 64);
    }
    if (l == 0) { red[og] = lsum; red[16 + og] = lsq; }
    __syncthreads();
    if (t == 0) {
        float a = 0.f, s2 = 0.f;
#pragma unroll
        for (int w = 0; w < 8; ++w) { a += red[w]; s2 += red[16 + w]; }
        atomicAdd(&accv[step * 16 + b * 2],     a);
        atomicAdd(&accv[step * 16 + b * 2 + 1], s2);
    }
}

// B+C1 fused, now MFMA: global LN0 -> hdn bf16 LDS -> fc1 GEMM (MFMA) ->
// mask + residual (in-place on x) -> parallel LN1 -> qkv GEMM (MFMA) ->
// LDS-staged vectorized qkv store.
__global__ __launch_bounds__(512) void k_update_qkv(
    float* __restrict__ xio, const bf16* __restrict__ hd,
    const short* __restrict__ fc1s, const void* __restrict__ n0w,
    const void* __restrict__ n0b, const void* __restrict__ mraw,
    const int* __restrict__ mflags, const float* __restrict__ accv,
    float* __restrict__ c0buf, const short* __restrict__ qkvs,
    const void* __restrict__ ln1w, const void* __restrict__ ln1b,
    bf16* __restrict__ qkv, int step)
{
    // hdn bf16 [64][136] @0 (17408); ts f32 [64][65] @17408 (16640);
    // ys bf16 [64][72] @34048 (9216); qo bf16 [64][200] @0 (25600, aliases
    // hdn+ts after both are dead). total 43264 B.
    __shared__ __align__(16) char sm[43264];
    short* hdn = (short*)sm;
    float* ts  = (float*)(sm + 17408);
    short* ys  = (short*)(sm + 34048);
    short* qo  = (short*)sm;

    int md = mflags[1];
    int bh = blockIdx.x;
    int b = bh >> 6, h = bh & 63;
    int t = threadIdx.x;
    const float invN = 1.f / 524288.f;
    float mean = accv[step * 16 + b * 2] * invN;
    float var  = accv[step * 16 + b * 2 + 1] * invN - mean * mean;
    float rstd = rsqrtf(fmaxf(var, 0.f) + 1e-5f);

    // LN0 -> hdn (bf16)
    const bf16* hrow = hd + ((b * 64 + h) * 64) * 128;
    for (int e = t; e < 1024; e += 512) {
        int pos = e >> 4, j8 = (e & 15) * 8;
        float hv[8], wv[8], bv[8], f[8];
        ld_bf8(hrow + pos * 128 + j8, hv);
        int ni = (h * 64 + pos) * 128 + j8;
        ldp8(n0w, ni, md, wv);
        ldp8(n0b, ni, md, bv);
#pragma unroll
        for (int j = 0; j < 8; ++j) f[j] = (hv[j] - mean) * rstd * wv[j] + bv[j];
        *(uint4*)&hdn[pos * 136 + j8] = pk_bf8(f);
    }
    __syncthreads();

    int og = __builtin_amdgcn_readfirstlane(t >> 6);
    int l = t & 63, nl = l & 15, q = l >> 4;

    // fc1 GEMM 64x64x128: wave og -> M-tile og&3, N-half og>>2. dx -> ts.
    {
        int mt = og & 3, nh = og >> 2;
        int o0 = nh * 32 + nl, o1 = o0 + 16;
        f32x4 a0 = (f32x4){0.f,0.f,0.f,0.f}, a1 = (f32x4){0.f,0.f,0.f,0.f};
#pragma unroll
        for (int kt = 0; kt < 4; ++kt) {
            bf16x8 av = *(const bf16x8*)&hdn[(mt * 16 + nl) * 136 + kt * 32 + q * 8];
            bf16x8 b0 = *(const bf16x8*)(fc1s + o0 * 128 + kt * 32 + q * 8);
            bf16x8 b1 = *(const bf16x8*)(fc1s + o1 * 128 + kt * 32 + q * 8);
            a0 = __builtin_amdgcn_mfma_f32_16x16x32_bf16(av, b0, a0, 0, 0, 0);
            a1 = __builtin_amdgcn_mfma_f32_16x16x32_bf16(av, b1, a1, 0, 0, 0);
        }
#pragma unroll
        for (int r2 = 0; r2 < 4; ++r2) {
            int m = mt * 16 + q * 4 + r2;
            ts[m * 65 + o0] = a0[r2];
            ts[m * 65 + o1] = a1[r2];
        }
    }
    __syncthreads();

    // mask + residual; xn back into ts (same slots) + xio + c0buf
    int cg = og;
    int pos = t & 63;
    {
        int mmode = mflags[0];
        int midx = ((step * 8 + b) * 64 + h) * 64 + pos;
        int mk;
        if (mmode == 0)      mk = ((const int*)mraw)[midx] != 0;
        else if (mmode == 1) mk = ((const unsigned char*)mraw)[midx] != 0;
        else if (mmode == 2) mk = ((const unsigned short*)mraw)[midx] != 0;
        else                 mk = ((const float*)mraw)[midx] != 0.0f;

        int idx = ((b * 64 + h) * 64 + pos) * 64 + cg * 8;
        float4 x0 = *(const float4*)&xio[idx];
        float4 x1 = *(const float4*)&xio[idx + 4];
        float xv[8] = {x0.x, x0.y, x0.z, x0.w, x1.x, x1.y, x1.z, x1.w};
        if (cg == 0) c0buf[(b * 64 + h) * 64 + pos] = xv[0];
        float* tp = &ts[pos * 65 + cg * 8];
        float xn[8];
#pragma unroll
        for (int ci = 0; ci < 8; ++ci) {
            xn[ci] = finz(mk ? (xv[ci] + tp[ci]) : xv[ci]);
            tp[ci] = xn[ci];
        }
        *(float4*)&xio[idx]     = make_float4(xn[0], xn[1], xn[2], xn[3]);
        *(float4*)&xio[idx + 4] = make_float4(xn[4], xn[5], xn[6], xn[7]);
    }
    __syncthreads();

    // ln1 parallel: 8 lanes per token -> ys bf16
    {
        int tok = t >> 3, j8 = (t & 7) * 8;
        float v[8];
        float ls = 0.f, lq = 0.f;
#pragma unroll
        for (int ci = 0; ci < 8; ++ci) {
            v[ci] = ts[tok * 65 + j8 + ci];
            ls += v[ci]; lq += v[ci] * v[ci];
        }
#pragma unroll
        for (int off = 1; off < 8; off <<= 1) {
            ls += __shfl_xor(ls, off, 64);
            lq += __shfl_xor(lq, off, 64);
        }
        float mu = ls * (1.f / 64.f);
        float vr = lq * (1.f / 64.f) - mu * mu;
        float rs = rsqrtf(fmaxf(vr, 0.f) + 1e-5f);
        float wv[8], bv[8];
        ldp8(ln1w, j8, md, wv);
        ldp8(ln1b, j8, md, bv);
        float yv[8];
#pragma unroll
        for (int ci = 0; ci < 8; ++ci) yv[ci] = (v[ci] - mu) * rs * wv[ci] + bv[ci];
        *(uint4*)&ys[tok * 72 + j8] = pk_bf8(yv);
    }
    __syncthreads();

    // qkv GEMM 64x192x64: wave og -> M-tile og&3, 6 N-tiles per half.
    // hdn+ts dead here -> qo may alias them.
    {
        int mt = og & 3, nh = og >> 2;
        f32x4 qa[6];
#pragma unroll
        for (int n = 0; n < 6; ++n) qa[n] = (f32x4){0.f, 0.f, 0.f, 0.f};
#pragma unroll
        for (int kt = 0; kt < 2; ++kt) {
            bf16x8 av = *(const bf16x8*)&ys[(mt * 16 + nl) * 72 + kt * 32 + q * 8];
#pragma unroll
            for (int n = 0; n < 6; ++n) {
                bf16x8 bv = *(const bf16x8*)(qkvs + (((nh * 6 + n) * 16) + nl) * 64 + kt * 32 + q * 8);
                qa[n] = __builtin_amdgcn_mfma_f32_16x16x32_bf16(av, bv, qa[n], 0, 0, 0);
            }
        }
#pragma unroll
        for (int n = 0; n < 6; ++n)
#pragma unroll
            for (int r2 = 0; r2 < 4; ++r2) {
                int m = mt * 16 + q * 4 + r2;
                qo[m * 200 + (nh * 6 + n) * 16 + nl] = (short)f2bfu(qa[n][r2]);
            }
    }
    __syncthreads();

    // vectorized qkv store
    for (int e = t; e < 1536; e += 512) {
        int p2 = e / 24, c8 = e - p2 * 24;
        *(uint4*)(qkv + ((bh << 6) + p2) * 192 + c8 * 8) =
            *(const uint4*)&qo[p2 * 200 + c8 * 8];
    }
}

// C2+D fused: attention (VALU, bf16 LDS, dedup'd) + out-proj/MLP1/MLP2 on
// MFMA + parallel ln2.
__global__ __launch_bounds__(512) void k_attn_ff(
    const bf16* __restrict__ qkv, float* __restrict__ xio,
    const float* __restrict__ c0buf, const short* __restrict__ outs,
    const short* __restrict__ ff1s, const short* __restrict__ ff2s,
    const void* __restrict__ outb, const void* __restrict__ ln2w,
    const void* __restrict__ ln2b, const void* __restrict__ ff1b,
    const void* __restrict__ ff2b, const int* __restrict__ mflags,
    void* __restrict__ dout, int write_out)
{
    // phase A: Ks bf16 [3][66][72] @0 (28512); Vs same @28512 (28512) = 57024.
    // phase B: Ao bf16 [64][72] @0 (9216); ts f32 [64][65] @9216 (16640);
    // ys bf16 [64][72] @25856; hs bf16 [64][72] @35072. total 44288 < 57024.
    __shared__ __align__(16) char smraw[57024];
    short* Ks = (short*)smraw;
    short* Vs = (short*)(smraw + 28512);
    short* Ao = (short*)smraw;
    float* ts = (float*)(smraw + 9216);
    short* ys = (short*)(smraw + 25856);
    short* hs = (short*)(smraw + 35072);

    int md = mflags[1];
    int bh = blockIdx.x;
    int b = bh >> 6, h = bh & 63;
    int t = threadIdx.x;

    // zero halo columns (w=0, w=65) of K and V
    if (t < 96) {
        int kind = (t >= 48) ? 1 : 0, u = t - kind * 48;
        int r = u >> 4, side = (u >> 3) & 1, c8 = u & 7;
        short* dst = kind ? Vs : Ks;
        uint4 z = {0, 0, 0, 0};
        *(uint4*)&dst[((r * 66) + (side ? 65 : 0)) * 72 + c8 * 8] = z;
    }
    // K + V staging: raw bf16 uint4 copies, no conversion
    for (int e = t; e < 3072; e += 512) {
        int kind = (e >= 1536) ? 1 : 0, u = e - kind * 1536;
        int c8 = u & 7, w = (u >> 3) & 63, r = u >> 9;
        int hr = h - 1 + r;
        uint4 v = {0, 0, 0, 0};
        if (hr >= 0 && hr <= 63)
            v = *(const uint4*)(qkv + ((b * 64 + hr) * 64 + w) * 192 + 64 + kind * 64 + c8 * 8);
        short* dst = kind ? Vs : Ks;
        *(uint4*)&dst[((r * 66) + w + 1) * 72 + c8 * 8] = v;
    }
    __syncthreads();

    int head = __builtin_amdgcn_readfirstlane(t >> 6) & 3;
    int pos  = t & 63;
    bool act = t < 256;   // waves 4..7 skip attention (was duplicated work)
    float o[16];
    if (act) {
        float qv[16];
        const bf16* qr = qkv + (((b * 64 + h) * 64) + pos) * 192 + head * 16;
        ld_bf8(qr, qv); ld_bf8(qr + 8, qv + 8);

        float a9[9];
#pragma unroll
        for (int r = 0; r < 3; ++r)
#pragma unroll
            for (int cxi = 0; cxi < 3; ++cxi) {
                const short* kp = &Ks[((r * 66) + pos + cxi) * 72 + head * 16];
                float kf[16];
                ld_bf8((const bf16*)kp, kf);
                ld_bf8((const bf16*)(kp + 8), kf + 8);
                float dot = 0.f;
#pragma unroll
                for (int d = 0; d < 16; ++d) dot = fmaf(qv[d], kf[d], dot);
                a9[r * 3 + cxi] = dot * 0.25f;
            }
        float mx = a9[0];
#pragma unroll
        for (int k = 1; k < 9; ++k) mx = fmaxf(mx, a9[k]);
        float ssum = 0.f;
#pragma unroll
        for (int k = 0; k < 9; ++k) { a9[k] = __expf(a9[k] - mx); ssum += a9[k]; }
        float inv = 1.f / ssum;
#pragma unroll
        for (int k = 0; k < 9; ++k) a9[k] *= inv;

#pragma unroll
        for (int d = 0; d < 16; ++d) o[d] = 0.f;
#pragma unroll
        for (int r = 0; r < 3; ++r)
#pragma unroll
            for (int cxi = 0; cxi < 3; ++cxi) {
                const short* vp = &Vs[((r * 66) + pos + cxi) * 72 + head * 16];
                float vf[16];
                ld_bf8((const bf16*)vp, vf);
                ld_bf8((const bf16*)(vp + 8), vf + 8);
                float w = a9[r * 3 + cxi];
#pragma unroll
                for (int d = 0; d < 16; ++d) o[d] = fmaf(w, vf[d], o[d]);
            }
    }
    __syncthreads();   // Ks/Vs dead; regions reused below
    if (act) {
        *(uint4*)&Ao[pos * 72 + head * 16]     = pk_bf8(o);
        *(uint4*)&Ao[pos * 72 + head * 16 + 8] = pk_bf8(o + 8);
    }
    __syncthreads();

    // ---- MFMA phases: 64x64x64 GEMMs, wave og: mt = og&3, n-tiles {nt0,nt0+1}
    int og = __builtin_amdgcn_readfirstlane(t >> 6);
    int l = t & 63, nl = l & 15, qd = l >> 4;
    int mt = og & 3;
    int nt0 = (og >> 2) * 2;
    int o0 = nt0 * 16 + nl, o1 = o0 + 16;

    // out-proj
    {
        f32x4 pa[2];
        pa[0] = (f32x4){0.f,0.f,0.f,0.f}; pa[1] = (f32x4){0.f,0.f,0.f,0.f};
#pragma unroll
        for (int kt = 0; kt < 2; ++kt) {
            bf16x8 av = *(const bf16x8*)&Ao[(mt * 16 + nl) * 72 + kt * 32 + qd * 8];
            bf16x8 b0 = *(const bf16x8*)(outs + o0 * 64 + kt * 32 + qd * 8);
            bf16x8 b1 = *(const bf16x8*)(outs + o1 * 64 + kt * 32 + qd * 8);
            pa[0] = __builtin_amdgcn_mfma_f32_16x16x32_bf16(av, b0, pa[0], 0, 0, 0);
            pa[1] = __builtin_amdgcn_mfma_f32_16x16x32_bf16(av, b1, pa[1], 0, 0, 0);
        }
        float ob0 = ldp(outb, o0, md), ob1 = ldp(outb, o1, md);
#pragma unroll
        for (int j = 0; j < 2; ++j)
#pragma unroll
            for (int r2 = 0; r2 < 4; ++r2) {
                int m = mt * 16 + qd * 4 + r2;
                ts[m * 65 + (j ? o1 : o0)] = pa[j][r2] + (j ? ob1 : ob0);
            }
    }
    __syncthreads();

    // residual add (vectorized xio read)
    int idx = ((bh << 6) + pos) * 64 + (t >> 6) * 8;
    {
        int cg2 = t >> 6;
        float4 x0 = *(const float4*)&xio[idx];
        float4 x1 = *(const float4*)&xio[idx + 4];
        float* tp = &ts[pos * 65 + cg2 * 8];
        tp[0] += x0.x; tp[1] += x0.y; tp[2] += x0.z; tp[3] += x0.w;
        tp[4] += x1.x; tp[5] += x1.y; tp[6] += x1.z; tp[7] += x1.w;
    }
    __syncthreads();

    // ln2 parallel (8 lanes/token) -> ys bf16
    {
        int tok = t >> 3, j8 = (t & 7) * 8;
        float v[8];
        float ls = 0.f, lq = 0.f;
#pragma unroll
        for (int ci = 0; ci < 8; ++ci) {
            v[ci] = ts[tok * 65 + j8 + ci];
            ls += v[ci]; lq += v[ci] * v[ci];
        }
#pragma unroll
        for (int off = 1; off < 8; off <<= 1) {
            ls += __shfl_xor(ls, off, 64);
            lq += __shfl_xor(lq, off, 64);
        }
        float mu = ls * (1.f / 64.f);
        float vr = lq * (1.f / 64.f) - mu * mu;
        float rs = rsqrtf(fmaxf(vr, 0.f) + 1e-5f);
        float wv[8], bv[8];
        ldp8(ln2w, j8, md, wv);
        ldp8(ln2b, j8, md, bv);
        float yv[8];
#pragma unroll
        for (int ci = 0; ci < 8; ++ci) yv[ci] = (v[ci] - mu) * rs * wv[ci] + bv[ci];
        *(uint4*)&ys[tok * 72 + j8] = pk_bf8(yv);
    }
    __syncthreads();

    // MLP1 + exact GELU -> hs bf16
    {
        f32x4 ma[2];
        ma[0] = (f32x4){0.f,0.f,0.f,0.f}; ma[1] = (f32x4){0.f,0.f,0.f,0.f};
#pragma unroll
        for (int kt = 0; kt < 2; ++kt) {
            bf16x8 av = *(const bf16x8*)&ys[(mt * 16 + nl) * 72 + kt * 32 + qd * 8];
            bf16x8 b0 = *(const bf16x8*)(ff1s + o0 * 64 + kt * 32 + qd * 8);
            bf16x8 b1 = *(const bf16x8*)(ff1s + o1 * 64 + kt * 32 + qd * 8);
            ma[0] = __builtin_amdgcn_mfma_f32_16x16x32_bf16(av, b0, ma[0], 0, 0, 0);
            ma[1] = __builtin_amdgcn_mfma_f32_16x16x32_bf16(av, b1, ma[1], 0, 0, 0);
        }
        float f1b0 = ldp(ff1b, o0, md), f1b1 = ldp(ff1b, o1, md);
#pragma unroll
        for (int j = 0; j < 2; ++j)
#pragma unroll
            for (int r2 = 0; r2 < 4; ++r2) {
                int m = mt * 16 + qd * 4 + r2;
                float v = ma[j][r2] + (j ? f1b1 : f1b0);
                float g = 0.5f * v * (1.f + erff(v * 0.70710678118654752f));
                hs[m * 72 + (j ? o1 : o0)] = (short)f2bfu(g);
            }
    }
    __syncthreads();

    // MLP2 + residual into ts
    {
        f32x4 fa[2];
        fa[0] = (f32x4){0.f,0.f,0.f,0.f}; fa[1] = (f32x4){0.f,0.f,0.f,0.f};
#pragma unroll
        for (int kt = 0; kt < 2; ++kt) {
            bf16x8 av = *(const bf16x8*)&hs[(mt * 16 + nl) * 72 + kt * 32 + qd * 8];
            bf16x8 b0 = *(const bf16x8*)(ff2s + o0 * 64 + kt * 32 + qd * 8);
            bf16x8 b1 = *(const bf16x8*)(ff2s + o1 * 64 + kt * 32 + qd * 8);
            fa[0] = __builtin_amdgcn_mfma_f32_16x16x32_bf16(av, b0, fa[0], 0, 0, 0);
            fa[1] = __builtin_amdgcn_mfma_f32_16x16x32_bf16(av, b1, fa[1], 0, 0, 0);
        }
        float f2b0 = ldp(ff2b, o0, md), f2b1 = ldp(ff2b, o1, md);
#pragma unroll
        for (int j = 0; j < 2; ++j)
#pragma unroll
            for (int r2 = 0; r2 < 4; ++r2) {
                int m = mt * 16 + qd * 4 + r2;
                int oo = j ? o1 : o0;
                ts[m * 65 + oo] += fa[j][r2] + (j ? f2b1 : f2b0);
            }
    }
    __syncthreads();

    // final write: ch0 restore + state + optional out (vectorized)
    {
        int cg2 = t >> 6;
        float fv[8];
#pragma unroll
        for (int ci = 0; ci < 8; ++ci) {
            float v = ts[pos * 65 + cg2 * 8 + ci];
            if (cg2 == 0 && ci == 0) v = c0buf[(bh << 6) + pos];
            fv[ci] = finz(v);
        }
        *(float4*)&xio[idx]     = make_float4(fv[0], fv[1], fv[2], fv[3]);
        *(float4*)&xio[idx + 4] = make_float4(fv[4], fv[5], fv[6], fv[7]);
        if (write_out) {
            if (md) {
                *(float4*)&((float*)dout)[idx]     = make_float4(fv[0], fv[1], fv[2], fv[3]);
                *(float4*)&((float*)dout)[idx + 4] = make_float4(fv[4], fv[5], fv[6], fv[7]);
            } else {
                *(uint4*)&((bf16*)dout)[idx] = pk_bf8(fv);
            }
        }
    }
}

// ---------------- launch ----------------

extern "C" void kernel_launch(void* const* d_in, const int* in_sizes, int n_in,
                              void* d_out, int out_size, void* d_ws, size_t ws_size,
                              hipStream_t stream) {
    (void)in_sizes; (void)n_in; (void)out_size; (void)ws_size;
    const void* x     = d_in[0];
    const void* masks = d_in[1];
    const void* p0w   = d_in[2];
    const void* p0b   = d_in[3];
    const void* p1w   = d_in[4];
    const void* p1b   = d_in[5];
    const void* fc0w  = d_in[6];
    const void* fc0b  = d_in[7];
    const void* fc1w  = d_in[8];
    const void* n0w   = d_in[9];
    const void* n0b   = d_in[10];
    const void* ln1w  = d_in[11];
    const void* ln1b  = d_in[12];
    const void* qkvw  = d_in[13];
    const void* outw  = d_in[14];
    const void* outb  = d_in[15];
    const void* ln2w  = d_in[16];
    const void* ln2b  = d_in[17];
    const void* ff1w  = d_in[18];
    const void* ff1b  = d_in[19];
    const void* ff2w  = d_in[20];
    const void* ff2b  = d_in[21];

    // workspace layout, ~29.8 MB (ws is 256 MiB per fill counter evidence).
    // hd and qkv un-aliased (old layout had a latent cross-block overlap).
    char* wsb = (char*)d_ws;
    float* xst    = (float*)(wsb + 0);           //  8,388,608 B fp32 state
    bf16*  hd     = (bf16*) (wsb + 8388608);     //  8,388,608 B
    bf16*  qkvb   = (bf16*) (wsb + 16777216);    // 12,582,912 B
    float* c0buf  = (float*)(wsb + 29360128);    //    131,072 B
    short* bt1    = (short*)(wsb + 29491200);    //    147,456 B
    short* packs  = (short*)(wsb + 29638656);    //    114,688 B
    float* accv   = (float*)(wsb + 29753344);    //        384 B
    int*   mflags = (int*)  (wsb + 29753728);    //         16 B

    short* fc0s = packs;            // 24576 bf16 [128][192]
    short* fc1s = packs + 24576;    //  8192 bf16 [64][128]
    short* qkvs = packs + 32768;    // 12288 bf16 [192][64]
    short* outs = packs + 45056;    //  4096 bf16 [64][64]
    short* ff1s = packs + 49152;    //  4096
    short* ff2s = packs + 53248;    //  4096

    k_detect<<<1, 256, 0, stream>>>((const uint4*)masks, (const uint4*)x, mflags, accv);
    k_cast<<<1024, 256, 0, stream>>>(x, xst, mflags, 262144);
    k_pack_bt1<<<288, 256, 0, stream>>>(p0w, p1w, bt1, mflags);
    k_pack_multi<<<224, 256, 0, stream>>>(fc0w, fc1w, qkvw, outw, ff1w, ff2w, packs, mflags);

    for (int s = 0; s < NSTEP; ++s) {
        k_perceive<<<512, 512, 0, stream>>>(xst, bt1, fc0s, p0b, p1b, fc0b, mflags, hd, accv, s);
        k_update_qkv<<<512, 512, 0, stream>>>(xst, hd, fc1s, n0w, n0b, masks, mflags, accv,
                                              c0buf, qkvs, ln1w, ln1b, qkvb, s);
        k_attn_ff<<<512, 512, 0, stream>>>(qkvb, xst, c0buf, outs, ff1s, ff2s,
                                           outb, ln2w, ln2b, ff1b, ff2b, mflags,
                                           d_out, (s == NSTEP - 1) ? 1 : 0);
    }
}